// Round 7
// baseline (39.233 us; speedup 1.0000x reference)
//
#include <hip/hip_runtime.h>

// Denoiser MLP (2->16, 5x 16->16, 16->2), fp32 in/out, via v_mfma_f32_32x32x16_f16.
// R7: kill constant-C rematerialization. R6 measured ~405 VALU instr/chunk vs
// ~110 ideal; the gap is the compiler re-zeroing the 16-VGPR C=0 operand
// before each of 14 MFMAs (16 v_mov x 14 = 224/chunk) plus weight-fragment
// re-derivation under the squeezed VGPR=44 allocation. Fix: pin the zero
// tuple and all weight fragments in registers with opaque empty asm
// ("+v" constraints) so the allocator must keep them live and the MFMA uses
// D != C with no per-call zeroing.
//
// Mapping (proven in R6, absmax 7.8e-3):
//   A (32x16) = [W; W], B (16x32) = 32 points' features (transposed)
//   A frag: lane l holds A[i=l&31][k=8*(l>>5)+j]
//   B frag: lane l holds B[k=8*(l>>5)+j][n=l&31]
//   D frag: lane l holds D[i=(reg&3)+8*(reg>>2)+4*(l>>5)][n=l&31]
// D regs 0-7 at hi=l>>5 = rows {0-3,8-11}/{4-7,12-15}; next-layer weights
// column-permuted [0-3,8-11 | 4-7,12-15] -> layers chain in register order,
// zero cross-lane traffic.

typedef _Float16 h8 __attribute__((ext_vector_type(8)));
typedef float f16v __attribute__((ext_vector_type(16)));
typedef float f4 __attribute__((ext_vector_type(4)));
typedef float f2 __attribute__((ext_vector_type(2)));
typedef unsigned int u32;
typedef u32 u4v __attribute__((ext_vector_type(4)));

static __device__ __forceinline__ f16v mfma32(h8 a, h8 b, f16v c) {
    return __builtin_amdgcn_mfma_f32_32x32x16_f16(a, b, c, 0, 0, 0);
}

static __device__ __forceinline__ u32 cvtpk(float a, float b) {
    return __builtin_bit_cast(u32, __builtin_amdgcn_cvt_pkrtz(a, b));
}

static __device__ __forceinline__ h8 pack4(u32 a, u32 b, u32 c, u32 d) {
    u4v p = {a, b, c, d};
    return __builtin_bit_cast(h8, p);
}

// quad-permuted weight fragment: j0-3 = cols 4*hi.., j4-7 = cols 8+4*hi..
static __device__ __forceinline__ h8 wfrag(const float* row, int hi) {
    const f4* r4 = (const f4*)row;
    f4 q0 = r4[hi], q1 = r4[hi + 2];
    return pack4(cvtpk(q0.x, q0.y), cvtpk(q0.z, q0.w),
                 cvtpk(q1.x, q1.y), cvtpk(q1.z, q1.w));
}

// relu + cvt of D regs 0-7 -> next layer's B fragment (order-preserving)
static __device__ __forceinline__ h8 cvt_relu8(f16v a) {
    h8 hb = pack4(cvtpk(a[0], a[1]), cvtpk(a[2], a[3]),
                  cvtpk(a[4], a[5]), cvtpk(a[6], a[7]));
    const h8 z = {};
    return __builtin_elementwise_max(hb, z);   // 4x v_pk_max_f16
}

__global__ __launch_bounds__(256) void denoiser_mfma32(
    const f2* __restrict__ x,        // [N] points (x0,x1)
    const float* __restrict__ w_in,  // [16][2]
    const float* __restrict__ w_mid, // [5][16][16]
    const float* __restrict__ w_out, // [2][16]
    f2* __restrict__ out,            // [N] (o0,o1)
    int n)
{
    const int lane = threadIdx.x & 63;
    const int m    = lane & 15;   // weight row (rows duplicated mod 16)
    const int hi   = lane >> 5;   // half-wave / k-group
    const int wave = threadIdx.x >> 6;

    const h8 hz = {};

    // ---- one-time weight fragments ----
    u32 wxy = cvtpk(w_in[2 * m], w_in[2 * m + 1]);
    h8 wi0 = hi == 0 ? pack4(wxy, 0u, 0u, 0u) : hz;   // stream0: k0,k1
    h8 wi1 = hi == 1 ? pack4(wxy, 0u, 0u, 0u) : hz;   // stream1: k8,k9

    h8 wm0 = wfrag(w_mid + 0 * 256 + m * 16, hi);
    h8 wm1 = wfrag(w_mid + 1 * 256 + m * 16, hi);
    h8 wm2 = wfrag(w_mid + 2 * 256 + m * 16, hi);
    h8 wm3 = wfrag(w_mid + 3 * 256 + m * 16, hi);
    h8 wm4 = wfrag(w_mid + 4 * 256 + m * 16, hi);

    h8 wo = m < 2 ? wfrag(w_out + m * 16, hi) : hz;

    // ---- opaque pins: force all of these to stay in registers, and make
    // z16 un-rematerializable (compiler can't see it's constant zero) ----
    f16v z16 = {};
    asm("" : "+v"(z16));
    asm("" : "+v"(wi0), "+v"(wi1), "+v"(wo));
    asm("" : "+v"(wm0), "+v"(wm1), "+v"(wm2), "+v"(wm3), "+v"(wm4));

    const int nchunks = (n + 255) >> 8;     // 256 pts per block-iteration
    for (int c = blockIdx.x; c < nchunks; c += gridDim.x) {
        const int base = c * 256 + wave * 64;   // this wave's 64 points
        const bool full = (base + 64 <= n);     // wave-uniform

        f2 xy;
        if (full) {
            xy = x[base + lane];
        } else {
            int pi = base + lane;
            xy = x[pi < n ? pi : n - 1];
        }

        // ---- input layer: shared B, two half-masked A variants ----
        h8 bin = pack4(cvtpk(xy.x, xy.y), 0u, 0u, 0u);
        f16v a0 = mfma32(wi0, bin, z16);
        f16v a1 = mfma32(wi1, bin, z16);
        h8 b0 = cvt_relu8(a0);
        h8 b1 = cvt_relu8(a1);

        // ---- 5 mid layers ----
        a0 = mfma32(wm0, b0, z16);  a1 = mfma32(wm0, b1, z16);
        b0 = cvt_relu8(a0);         b1 = cvt_relu8(a1);
        a0 = mfma32(wm1, b0, z16);  a1 = mfma32(wm1, b1, z16);
        b0 = cvt_relu8(a0);         b1 = cvt_relu8(a1);
        a0 = mfma32(wm2, b0, z16);  a1 = mfma32(wm2, b1, z16);
        b0 = cvt_relu8(a0);         b1 = cvt_relu8(a1);
        a0 = mfma32(wm3, b0, z16);  a1 = mfma32(wm3, b1, z16);
        b0 = cvt_relu8(a0);         b1 = cvt_relu8(a1);
        a0 = mfma32(wm4, b0, z16);  a1 = mfma32(wm4, b1, z16);
        b0 = cvt_relu8(a0);         b1 = cvt_relu8(a1);

        // ---- output layer: rows 0,1 -> regs 0,1 @ hi=0 ----
        a0 = mfma32(wo, b0, z16);
        a1 = mfma32(wo, b1, z16);

        if (lane < 32) {
            int p0 = base + lane;
            if (full) {
                out[p0]      = (f2){a0[0], a0[1]};
                out[p0 + 32] = (f2){a1[0], a1[1]};
            } else {
                if (p0 < n)      out[p0]      = (f2){a0[0], a0[1]};
                if (p0 + 32 < n) out[p0 + 32] = (f2){a1[0], a1[1]};
            }
        }
    }
}

extern "C" void kernel_launch(void* const* d_in, const int* in_sizes, int n_in,
                              void* d_out, int out_size, void* d_ws, size_t ws_size,
                              hipStream_t stream) {
    const float* x     = (const float*)d_in[0];
    const float* w_in  = (const float*)d_in[1];
    const float* w_mid = (const float*)d_in[2];
    const float* w_out = (const float*)d_in[3];

    int n = in_sizes[0] / 2;          // number of points
    int nchunks = (n + 255) / 256;
    int blocks = nchunks < 2048 ? nchunks : 2048;  // persistent

    denoiser_mfma32<<<blocks, 256, 0, stream>>>(
        (const f2*)x, w_in, w_mid, w_out, (f2*)d_out, n);
}

// Round 8
// 33.542 us; speedup vs baseline: 1.1697x; 1.1697x over previous
//
#include <hip/hip_runtime.h>

// Denoiser MLP (2->16, 5x 16->16, 16->2), fp32 in/out, via v_mfma_f32_32x32x16_f16.
// R8: kill AGPR accumulator allocation.
// Evidence: Occupancy 28% (~2.3 waves/SIMD) despite launching 8 blocks/CU and
// CSV VGPR_Count=56 -- but live-value count is ~110. CSV reports arch-VGPRs
// only; MFMA accumulators went to AGPRs, inflating unified per-wave total
// past ~170 (occupancy cliff) AND adding ~224 v_accvgpr_read/write moves per
// chunk (the VALU bloat measured in R6/R7). Fix:
//  - __launch_bounds__(256, 4): allocator contract total <=128 regs/wave
//  - asm("" : "+v"(x)) laundering on every MFMA result + B fragment: pins
//    them to arch-VGPR class, so AGPR allocation would need copies both
//    ways -> allocator keeps everything in VGPRs, accvgpr traffic vanishes.
//
// Mapping (proven R6/R7, absmax 7.8e-3):
//   A (32x16) = [W; W], B (16x32) = 32 points' features (transposed)
//   A frag: lane l holds A[i=l&31][k=8*(l>>5)+j]
//   B frag: lane l holds B[k=8*(l>>5)+j][n=l&31]
//   D frag: lane l holds D[i=(reg&3)+8*(reg>>2)+4*(l>>5)][n=l&31]
// D regs 0-7 at hi=l>>5 = rows {0-3,8-11}/{4-7,12-15}; next-layer weights
// column-permuted [0-3,8-11 | 4-7,12-15] -> layers chain in register order,
// zero cross-lane traffic. Two independent 32-pt streams per wave (ILP).

typedef _Float16 h8 __attribute__((ext_vector_type(8)));
typedef float f16v __attribute__((ext_vector_type(16)));
typedef float f4 __attribute__((ext_vector_type(4)));
typedef float f2 __attribute__((ext_vector_type(2)));
typedef unsigned int u32;
typedef u32 u4v __attribute__((ext_vector_type(4)));

static __device__ __forceinline__ f16v mfma32(h8 a, h8 b, f16v c) {
    f16v d = __builtin_amdgcn_mfma_f32_32x32x16_f16(a, b, c, 0, 0, 0);
    asm("" : "+v"(d));            // force arch-VGPR result (no AGPR shuttle)
    return d;
}

static __device__ __forceinline__ u32 cvtpk(float a, float b) {
    return __builtin_bit_cast(u32, __builtin_amdgcn_cvt_pkrtz(a, b));
}

static __device__ __forceinline__ h8 pack4(u32 a, u32 b, u32 c, u32 d) {
    u4v p = {a, b, c, d};
    return __builtin_bit_cast(h8, p);
}

// quad-permuted weight fragment: j0-3 = cols 4*hi.., j4-7 = cols 8+4*hi..
static __device__ __forceinline__ h8 wfrag(const float* row, int hi) {
    const f4* r4 = (const f4*)row;
    f4 q0 = r4[hi], q1 = r4[hi + 2];
    return pack4(cvtpk(q0.x, q0.y), cvtpk(q0.z, q0.w),
                 cvtpk(q1.x, q1.y), cvtpk(q1.z, q1.w));
}

// relu + cvt of D regs 0-7 -> next layer's B fragment (order-preserving)
static __device__ __forceinline__ h8 cvt_relu8(f16v a) {
    h8 hb = pack4(cvtpk(a[0], a[1]), cvtpk(a[2], a[3]),
                  cvtpk(a[4], a[5]), cvtpk(a[6], a[7]));
    const h8 z = {};
    hb = __builtin_elementwise_max(hb, z);   // 4x v_pk_max_f16
    asm("" : "+v"(hb));                      // keep in arch VGPRs
    return hb;
}

__global__ __launch_bounds__(256, 4) void denoiser_mfma32(
    const f2* __restrict__ x,        // [N] points (x0,x1)
    const float* __restrict__ w_in,  // [16][2]
    const float* __restrict__ w_mid, // [5][16][16]
    const float* __restrict__ w_out, // [2][16]
    f2* __restrict__ out,            // [N] (o0,o1)
    int n)
{
    const int lane = threadIdx.x & 63;
    const int m    = lane & 15;   // weight row (rows duplicated mod 16)
    const int hi   = lane >> 5;   // half-wave / k-group
    const int wave = threadIdx.x >> 6;

    const h8 hz = {};

    // ---- one-time weight fragments ----
    u32 wxy = cvtpk(w_in[2 * m], w_in[2 * m + 1]);
    h8 wi0 = hi == 0 ? pack4(wxy, 0u, 0u, 0u) : hz;   // stream0: k0,k1
    h8 wi1 = hi == 1 ? pack4(wxy, 0u, 0u, 0u) : hz;   // stream1: k8,k9

    h8 wm0 = wfrag(w_mid + 0 * 256 + m * 16, hi);
    h8 wm1 = wfrag(w_mid + 1 * 256 + m * 16, hi);
    h8 wm2 = wfrag(w_mid + 2 * 256 + m * 16, hi);
    h8 wm3 = wfrag(w_mid + 3 * 256 + m * 16, hi);
    h8 wm4 = wfrag(w_mid + 4 * 256 + m * 16, hi);

    h8 wo = m < 2 ? wfrag(w_out + m * 16, hi) : hz;

    // opaque pins: keep weights + zero-C resident in arch VGPRs
    f16v z16 = {};
    asm("" : "+v"(z16));
    asm("" : "+v"(wi0), "+v"(wi1), "+v"(wo));
    asm("" : "+v"(wm0), "+v"(wm1), "+v"(wm2), "+v"(wm3), "+v"(wm4));

    const int nchunks = (n + 255) >> 8;     // 256 pts per block-iteration
    for (int c = blockIdx.x; c < nchunks; c += gridDim.x) {
        const int base = c * 256 + wave * 64;   // this wave's 64 points
        const bool full = (base + 64 <= n);     // wave-uniform

        f2 xy;
        if (full) {
            xy = x[base + lane];
        } else {
            int pi = base + lane;
            xy = x[pi < n ? pi : n - 1];
        }

        // ---- input layer: shared B, two half-masked A variants ----
        h8 bin = pack4(cvtpk(xy.x, xy.y), 0u, 0u, 0u);
        asm("" : "+v"(bin));
        f16v a0 = mfma32(wi0, bin, z16);
        f16v a1 = mfma32(wi1, bin, z16);
        h8 b0 = cvt_relu8(a0);
        h8 b1 = cvt_relu8(a1);

        // ---- 5 mid layers (two independent streams -> ILP) ----
        a0 = mfma32(wm0, b0, z16);  a1 = mfma32(wm0, b1, z16);
        b0 = cvt_relu8(a0);         b1 = cvt_relu8(a1);
        a0 = mfma32(wm1, b0, z16);  a1 = mfma32(wm1, b1, z16);
        b0 = cvt_relu8(a0);         b1 = cvt_relu8(a1);
        a0 = mfma32(wm2, b0, z16);  a1 = mfma32(wm2, b1, z16);
        b0 = cvt_relu8(a0);         b1 = cvt_relu8(a1);
        a0 = mfma32(wm3, b0, z16);  a1 = mfma32(wm3, b1, z16);
        b0 = cvt_relu8(a0);         b1 = cvt_relu8(a1);
        a0 = mfma32(wm4, b0, z16);  a1 = mfma32(wm4, b1, z16);
        b0 = cvt_relu8(a0);         b1 = cvt_relu8(a1);

        // ---- output layer: rows 0,1 -> regs 0,1 @ hi=0 ----
        a0 = mfma32(wo, b0, z16);
        a1 = mfma32(wo, b1, z16);

        if (lane < 32) {
            int p0 = base + lane;
            if (full) {
                out[p0]      = (f2){a0[0], a0[1]};
                out[p0 + 32] = (f2){a1[0], a1[1]};
            } else {
                if (p0 < n)      out[p0]      = (f2){a0[0], a0[1]};
                if (p0 + 32 < n) out[p0 + 32] = (f2){a1[0], a1[1]};
            }
        }
    }
}

extern "C" void kernel_launch(void* const* d_in, const int* in_sizes, int n_in,
                              void* d_out, int out_size, void* d_ws, size_t ws_size,
                              hipStream_t stream) {
    const float* x     = (const float*)d_in[0];
    const float* w_in  = (const float*)d_in[1];
    const float* w_mid = (const float*)d_in[2];
    const float* w_out = (const float*)d_in[3];

    int n = in_sizes[0] / 2;          // number of points
    int nchunks = (n + 255) / 256;
    int blocks = nchunks < 2048 ? nchunks : 2048;  // persistent

    denoiser_mfma32<<<blocks, 256, 0, stream>>>(
        (const f2*)x, w_in, w_mid, w_out, (f2*)d_out, n);
}

// Round 9
// 33.356 us; speedup vs baseline: 1.1762x; 1.0056x over previous
//
#include <hip/hip_runtime.h>

// Denoiser MLP (2->16, 5x 16->16, 16->2), fp32 in/out, via v_mfma_f32_32x32x16_f16.
// R9: minimal-clean codegen round. R6/R7 measured ~400 VALU instr per 64-pt
// iteration vs ~110 in source; candidates: AGPR accvgpr shuttles and/or the
// R7/R8 asm pins themselves (a "+v" tie on a 16-reg tuple can cost 16 movs
// per site). This round: NO pins except a single one-time pin on the zero
// C-operand (blocks per-MFMA re-zeroing; one-time cost), plus
// __launch_bounds__(256,4) so the unified-RF allocator has no pressure
// (~104 live regs < 128) and no reason to touch AGPRs.
//
// Mapping (verified R6-R8, absmax 7.8e-3):
//   A (32x16) = [W; W], B (16x32) = 32 points' features (transposed)
//   A frag: lane l holds A[i=l&31][k=8*(l>>5)+j]
//   B frag: lane l holds B[k=8*(l>>5)+j][n=l&31]
//   D frag: lane l holds D[i=(reg&3)+8*(reg>>2)+4*(l>>5)][n=l&31]
// D regs 0-7 at hi=l>>5 = rows {0-3,8-11}/{4-7,12-15}; next-layer weights
// column-permuted [0-3,8-11 | 4-7,12-15] -> layers chain in register order,
// zero cross-lane traffic. Two independent 32-pt streams per wave (ILP).

typedef _Float16 h8 __attribute__((ext_vector_type(8)));
typedef float f16v __attribute__((ext_vector_type(16)));
typedef float f4 __attribute__((ext_vector_type(4)));
typedef float f2 __attribute__((ext_vector_type(2)));
typedef unsigned int u32;
typedef u32 u4v __attribute__((ext_vector_type(4)));

static __device__ __forceinline__ f16v mfma32(h8 a, h8 b, f16v c) {
    return __builtin_amdgcn_mfma_f32_32x32x16_f16(a, b, c, 0, 0, 0);
}

static __device__ __forceinline__ u32 cvtpk(float a, float b) {
    return __builtin_bit_cast(u32, __builtin_amdgcn_cvt_pkrtz(a, b));
}

static __device__ __forceinline__ h8 pack4(u32 a, u32 b, u32 c, u32 d) {
    u4v p = {a, b, c, d};
    return __builtin_bit_cast(h8, p);
}

// quad-permuted weight fragment: j0-3 = cols 4*hi.., j4-7 = cols 8+4*hi..
static __device__ __forceinline__ h8 wfrag(const float* row, int hi) {
    const f4* r4 = (const f4*)row;
    f4 q0 = r4[hi], q1 = r4[hi + 2];
    return pack4(cvtpk(q0.x, q0.y), cvtpk(q0.z, q0.w),
                 cvtpk(q1.x, q1.y), cvtpk(q1.z, q1.w));
}

// relu + cvt of D regs 0-7 -> next layer's B fragment (order-preserving)
static __device__ __forceinline__ h8 cvt_relu8(f16v a) {
    h8 hb = pack4(cvtpk(a[0], a[1]), cvtpk(a[2], a[3]),
                  cvtpk(a[4], a[5]), cvtpk(a[6], a[7]));
    const h8 z = {};
    return __builtin_elementwise_max(hb, z);   // 4x v_pk_max_f16
}

__global__ __launch_bounds__(256, 4) void denoiser_mfma32(
    const f2* __restrict__ x,        // [N] points (x0,x1)
    const float* __restrict__ w_in,  // [16][2]
    const float* __restrict__ w_mid, // [5][16][16]
    const float* __restrict__ w_out, // [2][16]
    f2* __restrict__ out,            // [N] (o0,o1)
    int n)
{
    const int lane = threadIdx.x & 63;
    const int m    = lane & 15;   // weight row (rows duplicated mod 16)
    const int hi   = lane >> 5;   // half-wave / k-group
    const int wave = threadIdx.x >> 6;

    const h8 hz = {};

    // ---- one-time weight fragments ----
    u32 wxy = cvtpk(w_in[2 * m], w_in[2 * m + 1]);
    h8 wi0 = hi == 0 ? pack4(wxy, 0u, 0u, 0u) : hz;   // stream0: k0,k1
    h8 wi1 = hi == 1 ? pack4(wxy, 0u, 0u, 0u) : hz;   // stream1: k8,k9

    h8 wm0 = wfrag(w_mid + 0 * 256 + m * 16, hi);
    h8 wm1 = wfrag(w_mid + 1 * 256 + m * 16, hi);
    h8 wm2 = wfrag(w_mid + 2 * 256 + m * 16, hi);
    h8 wm3 = wfrag(w_mid + 3 * 256 + m * 16, hi);
    h8 wm4 = wfrag(w_mid + 4 * 256 + m * 16, hi);

    h8 wo = m < 2 ? wfrag(w_out + m * 16, hi) : hz;

    // single one-time pin: make the zero C-operand un-rematerializable
    // (without this the compiler may re-zero 16 VGPRs before each MFMA)
    f16v z16 = {};
    asm("" : "+v"(z16));

    const int nchunks = (n + 255) >> 8;     // 256 pts per block-iteration
    for (int c = blockIdx.x; c < nchunks; c += gridDim.x) {
        const int base = c * 256 + wave * 64;   // this wave's 64 points
        const bool full = (base + 64 <= n);     // wave-uniform

        f2 xy;
        if (full) {
            xy = x[base + lane];
        } else {
            int pi = base + lane;
            xy = x[pi < n ? pi : n - 1];
        }

        // ---- input layer: shared B, two half-masked A variants ----
        h8 bin = pack4(cvtpk(xy.x, xy.y), 0u, 0u, 0u);
        f16v a0 = mfma32(wi0, bin, z16);
        f16v a1 = mfma32(wi1, bin, z16);
        h8 b0 = cvt_relu8(a0);
        h8 b1 = cvt_relu8(a1);

        // ---- 5 mid layers (two independent streams -> ILP) ----
        a0 = mfma32(wm0, b0, z16);  a1 = mfma32(wm0, b1, z16);
        b0 = cvt_relu8(a0);         b1 = cvt_relu8(a1);
        a0 = mfma32(wm1, b0, z16);  a1 = mfma32(wm1, b1, z16);
        b0 = cvt_relu8(a0);         b1 = cvt_relu8(a1);
        a0 = mfma32(wm2, b0, z16);  a1 = mfma32(wm2, b1, z16);
        b0 = cvt_relu8(a0);         b1 = cvt_relu8(a1);
        a0 = mfma32(wm3, b0, z16);  a1 = mfma32(wm3, b1, z16);
        b0 = cvt_relu8(a0);         b1 = cvt_relu8(a1);
        a0 = mfma32(wm4, b0, z16);  a1 = mfma32(wm4, b1, z16);
        b0 = cvt_relu8(a0);         b1 = cvt_relu8(a1);

        // ---- output layer: rows 0,1 -> regs 0,1 @ hi=0 ----
        a0 = mfma32(wo, b0, z16);
        a1 = mfma32(wo, b1, z16);

        if (lane < 32) {
            int p0 = base + lane;
            if (full) {
                out[p0]      = (f2){a0[0], a0[1]};
                out[p0 + 32] = (f2){a1[0], a1[1]};
            } else {
                if (p0 < n)      out[p0]      = (f2){a0[0], a0[1]};
                if (p0 + 32 < n) out[p0 + 32] = (f2){a1[0], a1[1]};
            }
        }
    }
}

extern "C" void kernel_launch(void* const* d_in, const int* in_sizes, int n_in,
                              void* d_out, int out_size, void* d_ws, size_t ws_size,
                              hipStream_t stream) {
    const float* x     = (const float*)d_in[0];
    const float* w_in  = (const float*)d_in[1];
    const float* w_mid = (const float*)d_in[2];
    const float* w_out = (const float*)d_in[3];

    int n = in_sizes[0] / 2;          // number of points
    int nchunks = (n + 255) / 256;
    int blocks = nchunks < 2048 ? nchunks : 2048;  // persistent

    denoiser_mfma32<<<blocks, 256, 0, stream>>>(
        (const f2*)x, w_in, w_mid, w_out, (f2*)d_out, n);
}